// Round 1
// baseline (810.638 us; speedup 1.0000x reference)
//
#include <hip/hip_runtime.h>
#include <hip/hip_bf16.h>

#define D_MODEL 768
#define HEADS 12
#define DK 64
#define LSEQ 2048
#define BATCH 4
#define MTOT (BATCH*LSEQ)                  // 8192 rows
#define SCALING 0.35355339059327373f       // 64^-0.25

typedef unsigned short ushort_t;
typedef __attribute__((ext_vector_type(8))) short bf16x8;
typedef __attribute__((ext_vector_type(4))) float f32x4;
typedef __attribute__((ext_vector_type(8))) unsigned short ushort8;
typedef __attribute__((ext_vector_type(4))) unsigned short ushort4v;

__device__ __forceinline__ unsigned short f2bf(float f){
  union { float f; unsigned int u; } v; v.f = f;
  unsigned int r = v.u + 0x7fffu + ((v.u >> 16) & 1u);
  return (unsigned short)(r >> 16);
}

__device__ __forceinline__ void g2l16(const void* g, void* l){
  __builtin_amdgcn_global_load_lds((const __attribute__((address_space(1))) void*)g,
                                   (__attribute__((address_space(3))) void*)l, 16, 0, 0);
}

// swizzled LDS read: logical (row, 16B-chunk c16) -> physical chunk c16 ^ (row&7)
__device__ __forceinline__ bf16x8 ldswz(const ushort_t* base, int row, int c16){
  return *(const bf16x8*)((const char*)base + row*128 + (((c16) ^ (row & 7)) << 4));
}

// ---------------- pass A1: fp32 -> bf16 input conversion ----------------
__global__ __launch_bounds__(256) void convert_inputs(
    const float* __restrict__ q, const float* __restrict__ k, const float* __restrict__ v,
    ushort_t* __restrict__ oq, ushort_t* __restrict__ ok, ushort_t* __restrict__ ov){
  const float* s = blockIdx.z==0 ? q : (blockIdx.z==1 ? k : v);
  ushort_t* d    = blockIdx.z==0 ? oq : (blockIdx.z==1 ? ok : ov);
  size_t i = ((size_t)blockIdx.x*256 + threadIdx.x)*4;
  float4 f = *(const float4*)(s + i);
  ushort4v o; o.x=f2bf(f.x); o.y=f2bf(f.y); o.z=f2bf(f.z); o.w=f2bf(f.w);
  *(ushort4v*)(d + i) = o;
}

// ---------------- pass A2: weight transpose fp32[k][n] -> bf16[n][k] ----------------
__global__ __launch_bounds__(256) void transpose_w(
    const float* __restrict__ w0, const float* __restrict__ w1,
    const float* __restrict__ w2, const float* __restrict__ w3,
    ushort_t* __restrict__ o0, ushort_t* __restrict__ o1,
    ushort_t* __restrict__ o2, ushort_t* __restrict__ o3){
  const float* s; ushort_t* d;
  switch (blockIdx.z){
    case 0: s=w0; d=o0; break; case 1: s=w1; d=o1; break;
    case 2: s=w2; d=o2; break; default: s=w3; d=o3; break;
  }
  __shared__ float t[32][33];
  int tx = threadIdx.x, ty = threadIdx.y;
  int c0 = blockIdx.x*32, r0 = blockIdx.y*32;
  #pragma unroll
  for (int i=0;i<4;i++) t[ty*4+i][tx] = s[(size_t)(r0+ty*4+i)*D_MODEL + c0+tx];
  __syncthreads();
  #pragma unroll
  for (int i=0;i<4;i++) d[(size_t)(c0+ty*4+i)*D_MODEL + r0+tx] = f2bf(t[tx][ty*4+i]);
}

// ---------------- GEMM: C[M][N] = A[M][K] * Bt[N][K]^T, M tiles of 128, N tiles of 128, K=768
// MODE 0: QKV projection, z selects matrix; out bf16 scattered to [b][h][l][d], scale on Q/K.
// MODE 1: output projection + bias, fp32 out row-major.
template<int MODE>
__global__ __launch_bounds__(256) void gemm128(
    const ushort_t* __restrict__ A0, const ushort_t* __restrict__ A1, const ushort_t* __restrict__ A2,
    const ushort_t* __restrict__ B0, const ushort_t* __restrict__ B1, const ushort_t* __restrict__ B2,
    ushort_t* __restrict__ o0, ushort_t* __restrict__ o1, ushort_t* __restrict__ o2,
    const float* __restrict__ bias, float* __restrict__ outf)
{
  const ushort_t* A; const ushort_t* Bt; ushort_t* outb = nullptr; float scale = 1.f;
  if (MODE == 0){
    int z = blockIdx.z;
    A  = z==0 ? A0 : (z==1 ? A1 : A2);
    Bt = z==0 ? B0 : (z==1 ? B1 : B2);
    outb = z==0 ? o0 : (z==1 ? o1 : o2);
    scale = (z==2) ? 1.f : SCALING;
  } else { A = A0; Bt = B0; }

  __shared__ ushort_t As[128*64];
  __shared__ ushort_t Bs[128*64];
  int tid = threadIdx.x;
  int w = tid >> 6, lane = tid & 63;
  int wm = w >> 1, wn = w & 1;
  int g = lane >> 4, li = lane & 15;
  size_t m0 = (size_t)blockIdx.y * 128;
  size_t n0 = (size_t)blockIdx.x * 128;

  f32x4 acc[4][4] = {};

  for (int kt = 0; kt < D_MODEL/64; ++kt){
    __syncthreads();
    int k0 = kt*64;
    #pragma unroll
    for (int i=0;i<4;i++){
      int row = i*32 + w*8 + (lane>>3);
      int c = (lane & 7) ^ (row & 7);
      g2l16(A  + (m0 + row)*D_MODEL + k0 + c*8, As + (i*32 + w*8)*64);
      g2l16(Bt + (n0 + row)*D_MODEL + k0 + c*8, Bs + (i*32 + w*8)*64);
    }
    __syncthreads();
    #pragma unroll
    for (int kc=0;kc<2;kc++){
      bf16x8 a[4], b[4];
      #pragma unroll
      for (int mt=0;mt<4;mt++) a[mt] = ldswz(As, wm*64 + mt*16 + li, kc*4 + g);
      #pragma unroll
      for (int nt=0;nt<4;nt++) b[nt] = ldswz(Bs, wn*64 + nt*16 + li, kc*4 + g);
      #pragma unroll
      for (int mt=0;mt<4;mt++)
        #pragma unroll
        for (int nt=0;nt<4;nt++)
          acc[mt][nt] = __builtin_amdgcn_mfma_f32_16x16x32_bf16(a[mt], b[nt], acc[mt][nt], 0,0,0);
    }
  }

  #pragma unroll
  for (int mt=0;mt<4;mt++){
    #pragma unroll
    for (int nt=0;nt<4;nt++){
      #pragma unroll
      for (int r=0;r<4;r++){
        int m = (int)m0 + wm*64 + mt*16 + g*4 + r;
        int n = (int)n0 + wn*64 + nt*16 + li;
        float v = acc[mt][nt][r];
        if (MODE == 0){
          v *= scale;
          int bb = m >> 11, l = m & (LSEQ-1), hh = n >> 6, dd = n & 63;
          outb[((((size_t)bb*HEADS + hh)*LSEQ + l) << 6) + dd] = f2bf(v);
        } else {
          outf[(size_t)m*D_MODEL + n] = v + bias[n];
        }
      }
    }
  }
}

// ---------------- pass B2: V [b][h][l][d] -> Vt [b][h][d][l] ----------------
__global__ __launch_bounds__(256) void transpose_v(
    const ushort_t* __restrict__ vp, ushort_t* __restrict__ vt){
  __shared__ ushort_t tile[64][65];
  int tid = threadIdx.x;
  int lt = blockIdx.x;            // l-tile 0..31
  size_t bh = blockIdx.y;         // 0..47
  const ushort_t* src = vp + (bh*LSEQ + (size_t)lt*64)*64;
  #pragma unroll
  for (int i=0;i<2;i++){
    int row = i*32 + (tid>>3);
    int c = tid & 7;
    ushort8 vv = *(const ushort8*)(src + row*64 + c*8);
    #pragma unroll
    for (int j=0;j<8;j++) tile[row][c*8+j] = vv[j];
  }
  __syncthreads();
  ushort_t* dst = vt + bh*64*LSEQ + (size_t)lt*64;
  #pragma unroll
  for (int i=0;i<2;i++){
    int d = i*32 + (tid>>3);
    int c = tid & 7;
    ushort8 vv;
    #pragma unroll
    for (int j=0;j<8;j++) vv[j] = tile[c*8+j][d];
    *(ushort8*)(dst + (size_t)d*LSEQ + c*8) = vv;
  }
}

// ---------------- pass C: flash attention ----------------
// block = 1 (b,h,qtile of 64 rows), 4 waves x 16 q-rows. KV tiles of 64.
__global__ __launch_bounds__(256) void attn(
    const ushort_t* __restrict__ Q, const ushort_t* __restrict__ Kp,
    const ushort_t* __restrict__ Vt, const float* __restrict__ PB,
    ushort_t* __restrict__ AO)
{
  __shared__ ushort_t ks[2][64*64];
  __shared__ ushort_t vs[2][64*64];
  __shared__ ushort_t ps[4][16*64];
  int tid = threadIdx.x, w = tid >> 6, lane = tid & 63;
  int g = lane >> 4, li = lane & 15;
  int bidx = blockIdx.x;
  int b = bidx & 3;                // batch fastest -> 4 batches stream same posbias -> L3 reuse
  int h = (bidx >> 2) % HEADS;
  int qt = bidx / (4*HEADS);
  size_t bh = (size_t)b*HEADS + h;
  const ushort_t* qb = Q  + bh*(LSEQ*64);
  const ushort_t* kb = Kp + bh*(LSEQ*64);
  const ushort_t* vb = Vt + bh*(64*LSEQ);

  int q0 = qt*64 + w*16;
  bf16x8 qf[2];
  #pragma unroll
  for (int kc=0;kc<2;kc++)
    qf[kc] = *(const bf16x8*)(qb + (size_t)(q0 + li)*64 + kc*32 + g*8);

  f32x4 oa[4] = {};
  float mrun[4], lrun[4];
  #pragma unroll
  for (int r=0;r<4;r++){ mrun[r] = -3e38f; lrun[r] = 0.f; }

  auto stage = [&](int t, int buf){
    #pragma unroll
    for (int i=0;i<2;i++){
      int row = i*32 + w*8 + (lane>>3);
      int c = (lane & 7) ^ (row & 7);
      g2l16(kb + ((size_t)t*64 + row)*64 + c*8, &ks[buf][(i*32 + w*8)*64]);
      g2l16(vb + (size_t)row*LSEQ + t*64 + c*8, &vs[buf][(i*32 + w*8)*64]);
    }
  };

  stage(0, 0);
  __syncthreads();

  const float* pbq = PB + ((size_t)h*LSEQ + q0 + g*4)*LSEQ;

  for (int t=0; t<LSEQ/64; ++t){
    int buf = t & 1;
    if (t+1 < LSEQ/64) stage(t+1, buf^1);

    // S = Q K^T (scaling pre-baked into Q,K)
    f32x4 s[4] = {};
    #pragma unroll
    for (int kc=0;kc<2;kc++){
      #pragma unroll
      for (int nt=0;nt<4;nt++){
        bf16x8 kf = ldswz(ks[buf], nt*16 + li, kc*4 + g);
        s[nt] = __builtin_amdgcn_mfma_f32_16x16x32_bf16(qf[kc], kf, s[nt], 0,0,0);
      }
    }
    // + posbias  (C layout: row q = g*4+r, col kv = nt*16+li)
    #pragma unroll
    for (int r=0;r<4;r++){
      const float* pr = pbq + (size_t)r*LSEQ + (size_t)t*64 + li;
      #pragma unroll
      for (int nt=0;nt<4;nt++) s[nt][r] += pr[nt*16];
    }
    // online softmax across the 16-lane group (one q-row lives in 16 lanes x 4 regs)
    float al[4];
    #pragma unroll
    for (int r=0;r<4;r++){
      float mx = fmaxf(fmaxf(s[0][r], s[1][r]), fmaxf(s[2][r], s[3][r]));
      #pragma unroll
      for (int d=1; d<16; d<<=1) mx = fmaxf(mx, __shfl_xor(mx, d));
      float nm = fmaxf(mrun[r], mx);
      al[r] = __expf(mrun[r] - nm);
      mrun[r] = nm;
      float rs = 0.f;
      #pragma unroll
      for (int nt=0;nt<4;nt++){ float p = __expf(s[nt][r] - nm); s[nt][r] = p; rs += p; }
      #pragma unroll
      for (int d=1; d<16; d<<=1) rs += __shfl_xor(rs, d);
      lrun[r] = lrun[r]*al[r] + rs;
    }
    #pragma unroll
    for (int nt=0;nt<4;nt++)
      #pragma unroll
      for (int r=0;r<4;r++) oa[nt][r] *= al[r];

    // P -> per-wave LDS (bf16, swizzled); same-wave DS ops are in-order, no barrier needed
    #pragma unroll
    for (int r=0;r<4;r++){
      int row = g*4 + r;
      #pragma unroll
      for (int nt=0;nt<4;nt++){
        int colb = (nt*16 + li)*2;
        *(ushort_t*)((char*)ps[w] + row*128 + (colb ^ ((row&7)<<4))) = f2bf(s[nt][r]);
      }
    }
    // O += P V
    bf16x8 pa[2];
    #pragma unroll
    for (int kc=0;kc<2;kc++) pa[kc] = ldswz(ps[w], li, kc*4 + g);
    #pragma unroll
    for (int kc=0;kc<2;kc++){
      #pragma unroll
      for (int nt=0;nt<4;nt++){
        bf16x8 vf = ldswz(vs[buf], nt*16 + li, kc*4 + g);
        oa[nt] = __builtin_amdgcn_mfma_f32_16x16x32_bf16(pa[kc], vf, oa[nt], 0,0,0);
      }
    }
    __syncthreads();
  }

  #pragma unroll
  for (int r=0;r<4;r++){
    float inv = 1.f / lrun[r];
    size_t orow = ((size_t)b*LSEQ + q0 + g*4 + r)*D_MODEL + h*64;
    #pragma unroll
    for (int nt=0;nt<4;nt++)
      AO[orow + nt*16 + li] = f2bf(oa[nt][r] * inv);
  }
}

// ---------------- launcher ----------------
extern "C" void kernel_launch(void* const* d_in, const int* in_sizes, int n_in,
                              void* d_out, int out_size, void* d_ws, size_t ws_size,
                              hipStream_t stream){
  const float* q  = (const float*)d_in[0];
  const float* k  = (const float*)d_in[1];
  const float* v  = (const float*)d_in[2];
  const float* pb = (const float*)d_in[3];
  const float* Wq = (const float*)d_in[4];
  const float* Wk = (const float*)d_in[5];
  const float* Wv = (const float*)d_in[6];
  const float* Wo = (const float*)d_in[7];
  const float* bo = (const float*)d_in[8];
  float* out = (float*)d_out;

  char* ws = (char*)d_ws;
  size_t off = 0;
  const size_t XSZ = (size_t)MTOT*D_MODEL*2;   // 12.58 MB
  const size_t WSZ = (size_t)D_MODEL*D_MODEL*2;
  ushort_t* xq  = (ushort_t*)(ws + off); off += XSZ;
  ushort_t* xk  = (ushort_t*)(ws + off); off += XSZ;
  ushort_t* xv  = (ushort_t*)(ws + off); off += XSZ;
  ushort_t* wqt = (ushort_t*)(ws + off); off += WSZ;
  ushort_t* wkt = (ushort_t*)(ws + off); off += WSZ;
  ushort_t* wvt = (ushort_t*)(ws + off); off += WSZ;
  ushort_t* wot = (ushort_t*)(ws + off); off += WSZ;
  ushort_t* qp  = (ushort_t*)(ws + off); off += XSZ;
  ushort_t* kp  = (ushort_t*)(ws + off); off += XSZ;
  ushort_t* vp  = (ushort_t*)(ws + off); off += XSZ;
  ushort_t* vt  = (ushort_t*)(ws + off); off += XSZ;
  ushort_t* ao  = (ushort_t*)(ws + off); off += XSZ;

  convert_inputs<<<dim3(MTOT*D_MODEL/1024, 1, 3), 256, 0, stream>>>(q, k, v, xq, xk, xv);
  transpose_w<<<dim3(24, 24, 4), dim3(32, 8), 0, stream>>>(Wq, Wk, Wv, Wo, wqt, wkt, wvt, wot);
  gemm128<0><<<dim3(D_MODEL/128, MTOT/128, 3), 256, 0, stream>>>(
      xq, xk, xv, wqt, wkt, wvt, qp, kp, vp, nullptr, nullptr);
  transpose_v<<<dim3(LSEQ/64, BATCH*HEADS), 256, 0, stream>>>(vp, vt);
  attn<<<dim3((LSEQ/64)*HEADS*BATCH), 256, 0, stream>>>(qp, kp, vt, pb, ao);
  gemm128<1><<<dim3(D_MODEL/128, MTOT/128, 1), 256, 0, stream>>>(
      ao, nullptr, nullptr, wot, nullptr, nullptr, nullptr, nullptr, nullptr, bo, out);
}

// Round 2
// 700.825 us; speedup vs baseline: 1.1567x; 1.1567x over previous
//
#include <hip/hip_runtime.h>
#include <hip/hip_bf16.h>

#define D_MODEL 768
#define HEADS 12
#define DK 64
#define LSEQ 2048
#define BATCH 4
#define MTOT (BATCH*LSEQ)                  // 8192 rows
#define SCALING 0.35355339059327373f       // 64^-0.25

typedef unsigned short ushort_t;
typedef __attribute__((ext_vector_type(8))) short bf16x8;
typedef __attribute__((ext_vector_type(4))) float f32x4;
typedef __attribute__((ext_vector_type(8))) unsigned short ushort8;
typedef __attribute__((ext_vector_type(4))) unsigned short ushort4v;

__device__ __forceinline__ unsigned short f2bf(float f){
  union { float f; unsigned int u; } v; v.f = f;
  unsigned int r = v.u + 0x7fffu + ((v.u >> 16) & 1u);
  return (unsigned short)(r >> 16);
}

__device__ __forceinline__ float bf2f(unsigned short u){
  union { unsigned int u; float f; } v; v.u = ((unsigned int)u) << 16; return v.f;
}

__device__ __forceinline__ void g2l16(const void* g, void* l){
  __builtin_amdgcn_global_load_lds((const __attribute__((address_space(1))) void*)g,
                                   (__attribute__((address_space(3))) void*)l, 16, 0, 0);
}

// swizzled LDS read: logical (row, 16B-chunk c16) -> physical chunk c16 ^ (row&7)
__device__ __forceinline__ bf16x8 ldswz(const ushort_t* base, int row, int c16){
  return *(const bf16x8*)((const char*)base + row*128 + (((c16) ^ (row & 7)) << 4));
}

// scalar bf16 read from a 64-wide swizzled LDS row
__device__ __forceinline__ float ldswz_s(const ushort_t* base, int row, int col){
  int c16 = col >> 3;
  int off = row*128 + ((c16 ^ (row & 7)) << 4) + (col & 7)*2;
  return bf2f(*(const ushort_t*)((const char*)base + off));
}

// ---------------- pass A1: fp32 -> bf16 input conversion ----------------
__global__ __launch_bounds__(256) void convert_inputs(
    const float* __restrict__ q, const float* __restrict__ k, const float* __restrict__ v,
    ushort_t* __restrict__ oq, ushort_t* __restrict__ ok, ushort_t* __restrict__ ov){
  const float* s = blockIdx.z==0 ? q : (blockIdx.z==1 ? k : v);
  ushort_t* d    = blockIdx.z==0 ? oq : (blockIdx.z==1 ? ok : ov);
  size_t i = ((size_t)blockIdx.x*256 + threadIdx.x)*4;
  float4 f = *(const float4*)(s + i);
  ushort4v o; o.x=f2bf(f.x); o.y=f2bf(f.y); o.z=f2bf(f.z); o.w=f2bf(f.w);
  *(ushort4v*)(d + i) = o;
}

// ---------------- pass A1b: posbias fp32 -> bf16 ----------------
__global__ __launch_bounds__(256) void convert_bias(
    const float* __restrict__ pb, ushort_t* __restrict__ o){
  size_t i = ((size_t)blockIdx.x*256 + threadIdx.x)*8;
  float4 a = *(const float4*)(pb + i);
  float4 b = *(const float4*)(pb + i + 4);
  ushort8 v;
  v[0]=f2bf(a.x); v[1]=f2bf(a.y); v[2]=f2bf(a.z); v[3]=f2bf(a.w);
  v[4]=f2bf(b.x); v[5]=f2bf(b.y); v[6]=f2bf(b.z); v[7]=f2bf(b.w);
  *(ushort8*)(o + i) = v;
}

// ---------------- pass A2: weight transpose fp32[k][n] -> bf16[n][k] ----------------
__global__ __launch_bounds__(256) void transpose_w(
    const float* __restrict__ w0, const float* __restrict__ w1,
    const float* __restrict__ w2, const float* __restrict__ w3,
    ushort_t* __restrict__ o0, ushort_t* __restrict__ o1,
    ushort_t* __restrict__ o2, ushort_t* __restrict__ o3){
  const float* s; ushort_t* d;
  switch (blockIdx.z){
    case 0: s=w0; d=o0; break; case 1: s=w1; d=o1; break;
    case 2: s=w2; d=o2; break; default: s=w3; d=o3; break;
  }
  __shared__ float t[32][33];
  int tx = threadIdx.x, ty = threadIdx.y;
  int c0 = blockIdx.x*32, r0 = blockIdx.y*32;
  #pragma unroll
  for (int i=0;i<4;i++) t[ty*4+i][tx] = s[(size_t)(r0+ty*4+i)*D_MODEL + c0+tx];
  __syncthreads();
  #pragma unroll
  for (int i=0;i<4;i++) d[(size_t)(c0+ty*4+i)*D_MODEL + r0+tx] = f2bf(t[tx][ty*4+i]);
}

// ---------------- GEMM: C[M][N] = A[M][K] * Bt[N][K]^T ----------------
template<int MODE>
__global__ __launch_bounds__(256) void gemm128(
    const ushort_t* __restrict__ A0, const ushort_t* __restrict__ A1, const ushort_t* __restrict__ A2,
    const ushort_t* __restrict__ B0, const ushort_t* __restrict__ B1, const ushort_t* __restrict__ B2,
    ushort_t* __restrict__ o0, ushort_t* __restrict__ o1, ushort_t* __restrict__ o2,
    const float* __restrict__ bias, float* __restrict__ outf)
{
  const ushort_t* A; const ushort_t* Bt; ushort_t* outb = nullptr; float scale = 1.f;
  if (MODE == 0){
    int z = blockIdx.z;
    A  = z==0 ? A0 : (z==1 ? A1 : A2);
    Bt = z==0 ? B0 : (z==1 ? B1 : B2);
    outb = z==0 ? o0 : (z==1 ? o1 : o2);
    scale = (z==2) ? 1.f : SCALING;
  } else { A = A0; Bt = B0; }

  __shared__ ushort_t As[128*64];
  __shared__ ushort_t Bs[128*64];
  int tid = threadIdx.x;
  int w = tid >> 6, lane = tid & 63;
  int wm = w >> 1, wn = w & 1;
  int g = lane >> 4, li = lane & 15;
  size_t m0 = (size_t)blockIdx.y * 128;
  size_t n0 = (size_t)blockIdx.x * 128;

  f32x4 acc[4][4] = {};

  for (int kt = 0; kt < D_MODEL/64; ++kt){
    __syncthreads();
    int k0 = kt*64;
    #pragma unroll
    for (int i=0;i<4;i++){
      int row = i*32 + w*8 + (lane>>3);
      int c = (lane & 7) ^ (row & 7);
      g2l16(A  + (m0 + row)*D_MODEL + k0 + c*8, As + (i*32 + w*8)*64);
      g2l16(Bt + (n0 + row)*D_MODEL + k0 + c*8, Bs + (i*32 + w*8)*64);
    }
    __syncthreads();
    #pragma unroll
    for (int kc=0;kc<2;kc++){
      bf16x8 a[4], b[4];
      #pragma unroll
      for (int mt=0;mt<4;mt++) a[mt] = ldswz(As, wm*64 + mt*16 + li, kc*4 + g);
      #pragma unroll
      for (int nt=0;nt<4;nt++) b[nt] = ldswz(Bs, wn*64 + nt*16 + li, kc*4 + g);
      #pragma unroll
      for (int mt=0;mt<4;mt++)
        #pragma unroll
        for (int nt=0;nt<4;nt++)
          acc[mt][nt] = __builtin_amdgcn_mfma_f32_16x16x32_bf16(a[mt], b[nt], acc[mt][nt], 0,0,0);
    }
  }

  #pragma unroll
  for (int mt=0;mt<4;mt++){
    #pragma unroll
    for (int nt=0;nt<4;nt++){
      #pragma unroll
      for (int r=0;r<4;r++){
        int m = (int)m0 + wm*64 + mt*16 + g*4 + r;
        int n = (int)n0 + wn*64 + nt*16 + li;
        float v = acc[mt][nt][r];
        if (MODE == 0){
          v *= scale;
          int bb = m >> 11, l = m & (LSEQ-1), hh = n >> 6, dd = n & 63;
          outb[((((size_t)bb*HEADS + hh)*LSEQ + l) << 6) + dd] = f2bf(v);
        } else {
          outf[(size_t)m*D_MODEL + n] = v + bias[n];
        }
      }
    }
  }
}

// ---------------- pass B2: V [b][h][l][d] -> Vt [b][h][d][l] ----------------
__global__ __launch_bounds__(256) void transpose_v(
    const ushort_t* __restrict__ vp, ushort_t* __restrict__ vt){
  __shared__ ushort_t tile[64][65];
  int tid = threadIdx.x;
  int lt = blockIdx.x;
  size_t bh = blockIdx.y;
  const ushort_t* src = vp + (bh*LSEQ + (size_t)lt*64)*64;
  #pragma unroll
  for (int i=0;i<2;i++){
    int row = i*32 + (tid>>3);
    int c = tid & 7;
    ushort8 vv = *(const ushort8*)(src + row*64 + c*8);
    #pragma unroll
    for (int j=0;j<8;j++) tile[row][c*8+j] = vv[j];
  }
  __syncthreads();
  ushort_t* dst = vt + bh*64*LSEQ + (size_t)lt*64;
  #pragma unroll
  for (int i=0;i<2;i++){
    int d = i*32 + (tid>>3);
    int c = tid & 7;
    ushort8 vv;
    #pragma unroll
    for (int j=0;j<8;j++) vv[j] = tile[c*8+j][d];
    *(ushort8*)(dst + (size_t)d*LSEQ + c*8) = vv;
  }
}

// ---------------- pass C: flash attention ----------------
// block = 1 (b,h,qtile of 64 rows), 4 waves x 16 q-rows. KV tiles of 64.
// K, V, and posbias all ride the same double-buffered global_load_lds pipeline.
__global__ __launch_bounds__(256) void attn(
    const ushort_t* __restrict__ Q, const ushort_t* __restrict__ Kp,
    const ushort_t* __restrict__ Vt, const ushort_t* __restrict__ PBB,
    ushort_t* __restrict__ AO)
{
  __shared__ ushort_t ks[2][64*64];
  __shared__ ushort_t vs[2][64*64];
  __shared__ ushort_t bs[2][64*64];
  __shared__ ushort_t ps[4][16*64];
  int tid = threadIdx.x, w = tid >> 6, lane = tid & 63;
  int g = lane >> 4, li = lane & 15;
  int bidx = blockIdx.x;
  int b = bidx & 3;                // batch fastest -> 4 batches stream same posbias -> L3 reuse
  int h = (bidx >> 2) % HEADS;
  int qt = bidx / (4*HEADS);
  size_t bh = (size_t)b*HEADS + h;
  const ushort_t* qb = Q  + bh*(LSEQ*64);
  const ushort_t* kb = Kp + bh*(LSEQ*64);
  const ushort_t* vb = Vt + bh*(64*LSEQ);
  const ushort_t* pbb = PBB + ((size_t)h*LSEQ + qt*64)*LSEQ;

  int q0 = qt*64 + w*16;
  bf16x8 qf[2];
  #pragma unroll
  for (int kc=0;kc<2;kc++)
    qf[kc] = *(const bf16x8*)(qb + (size_t)(q0 + li)*64 + kc*32 + g*8);

  f32x4 oa[4] = {};
  float mrun[4], lrun[4];
  #pragma unroll
  for (int r=0;r<4;r++){ mrun[r] = -3e38f; lrun[r] = 0.f; }

  auto stage = [&](int t, int buf){
    #pragma unroll
    for (int i=0;i<2;i++){
      int row = i*32 + w*8 + (lane>>3);
      int c = (lane & 7) ^ (row & 7);
      g2l16(kb  + ((size_t)t*64 + row)*64 + c*8,   &ks[buf][(i*32 + w*8)*64]);
      g2l16(vb  + (size_t)row*LSEQ + t*64 + c*8,   &vs[buf][(i*32 + w*8)*64]);
      g2l16(pbb + (size_t)row*LSEQ + t*64 + c*8,   &bs[buf][(i*32 + w*8)*64]);
    }
  };

  stage(0, 0);
  __syncthreads();

  for (int t=0; t<LSEQ/64; ++t){
    int buf = t & 1;
    if (t+1 < LSEQ/64) stage(t+1, buf^1);

    // S = Q K^T (scaling pre-baked into Q,K)
    f32x4 s[4] = {};
    #pragma unroll
    for (int kc=0;kc<2;kc++){
      #pragma unroll
      for (int nt=0;nt<4;nt++){
        bf16x8 kf = ldswz(ks[buf], nt*16 + li, kc*4 + g);
        s[nt] = __builtin_amdgcn_mfma_f32_16x16x32_bf16(qf[kc], kf, s[nt], 0,0,0);
      }
    }
    // + posbias from prefetched LDS tile (C layout: row q = w*16+g*4+r, col kv = nt*16+li)
    #pragma unroll
    for (int r=0;r<4;r++){
      int row = w*16 + g*4 + r;
      #pragma unroll
      for (int nt=0;nt<4;nt++)
        s[nt][r] += ldswz_s(bs[buf], row, nt*16 + li);
    }
    // online softmax across the 16-lane group (one q-row lives in 16 lanes x 4 regs)
    float al[4];
    #pragma unroll
    for (int r=0;r<4;r++){
      float mx = fmaxf(fmaxf(s[0][r], s[1][r]), fmaxf(s[2][r], s[3][r]));
      #pragma unroll
      for (int d=1; d<16; d<<=1) mx = fmaxf(mx, __shfl_xor(mx, d));
      float nm = fmaxf(mrun[r], mx);
      al[r] = __expf(mrun[r] - nm);
      mrun[r] = nm;
      float rs = 0.f;
      #pragma unroll
      for (int nt=0;nt<4;nt++){ float p = __expf(s[nt][r] - nm); s[nt][r] = p; rs += p; }
      #pragma unroll
      for (int d=1; d<16; d<<=1) rs += __shfl_xor(rs, d);
      lrun[r] = lrun[r]*al[r] + rs;
    }
    #pragma unroll
    for (int nt=0;nt<4;nt++)
      #pragma unroll
      for (int r=0;r<4;r++) oa[nt][r] *= al[r];

    // P -> per-wave LDS (bf16, swizzled); same-wave DS ops are in-order, no barrier needed
    #pragma unroll
    for (int r=0;r<4;r++){
      int row = g*4 + r;
      #pragma unroll
      for (int nt=0;nt<4;nt++){
        int colb = (nt*16 + li)*2;
        *(ushort_t*)((char*)ps[w] + row*128 + (colb ^ ((row&7)<<4))) = f2bf(s[nt][r]);
      }
    }
    // O += P V
    bf16x8 pa[2];
    #pragma unroll
    for (int kc=0;kc<2;kc++) pa[kc] = ldswz(ps[w], li, kc*4 + g);
    #pragma unroll
    for (int kc=0;kc<2;kc++){
      #pragma unroll
      for (int nt=0;nt<4;nt++){
        bf16x8 vf = ldswz(vs[buf], nt*16 + li, kc*4 + g);
        oa[nt] = __builtin_amdgcn_mfma_f32_16x16x32_bf16(pa[kc], vf, oa[nt], 0,0,0);
      }
    }
    __syncthreads();
  }

  #pragma unroll
  for (int r=0;r<4;r++){
    float inv = 1.f / lrun[r];
    size_t orow = ((size_t)b*LSEQ + q0 + g*4 + r)*D_MODEL + h*64;
    #pragma unroll
    for (int nt=0;nt<4;nt++)
      AO[orow + nt*16 + li] = f2bf(oa[nt][r] * inv);
  }
}

// ---------------- launcher ----------------
extern "C" void kernel_launch(void* const* d_in, const int* in_sizes, int n_in,
                              void* d_out, int out_size, void* d_ws, size_t ws_size,
                              hipStream_t stream){
  const float* q  = (const float*)d_in[0];
  const float* k  = (const float*)d_in[1];
  const float* v  = (const float*)d_in[2];
  const float* pb = (const float*)d_in[3];
  const float* Wq = (const float*)d_in[4];
  const float* Wk = (const float*)d_in[5];
  const float* Wv = (const float*)d_in[6];
  const float* Wo = (const float*)d_in[7];
  const float* bo = (const float*)d_in[8];
  float* out = (float*)d_out;

  char* ws = (char*)d_ws;
  size_t off = 0;
  const size_t XSZ = (size_t)MTOT*D_MODEL*2;   // 12.58 MB
  const size_t WSZ = (size_t)D_MODEL*D_MODEL*2;
  const size_t PBSZ = (size_t)HEADS*LSEQ*LSEQ*2; // 100.66 MB
  ushort_t* xq  = (ushort_t*)(ws + off); off += XSZ;
  ushort_t* xk  = (ushort_t*)(ws + off); off += XSZ;
  ushort_t* xv  = (ushort_t*)(ws + off); off += XSZ;
  ushort_t* wqt = (ushort_t*)(ws + off); off += WSZ;
  ushort_t* wkt = (ushort_t*)(ws + off); off += WSZ;
  ushort_t* wvt = (ushort_t*)(ws + off); off += WSZ;
  ushort_t* wot = (ushort_t*)(ws + off); off += WSZ;
  ushort_t* qp  = (ushort_t*)(ws + off); off += XSZ;
  ushort_t* kp  = (ushort_t*)(ws + off); off += XSZ;
  ushort_t* vp  = (ushort_t*)(ws + off); off += XSZ;
  ushort_t* vt  = (ushort_t*)(ws + off); off += XSZ;
  ushort_t* ao  = (ushort_t*)(ws + off); off += XSZ;
  ushort_t* pbb = (ushort_t*)(ws + off); off += PBSZ;

  convert_inputs<<<dim3(MTOT*D_MODEL/1024, 1, 3), 256, 0, stream>>>(q, k, v, xq, xk, xv);
  convert_bias<<<dim3((int)((size_t)HEADS*LSEQ*LSEQ/2048)), 256, 0, stream>>>(pb, pbb);
  transpose_w<<<dim3(24, 24, 4), dim3(32, 8), 0, stream>>>(Wq, Wk, Wv, Wo, wqt, wkt, wvt, wot);
  gemm128<0><<<dim3(D_MODEL/128, MTOT/128, 3), 256, 0, stream>>>(
      xq, xk, xv, wqt, wkt, wvt, qp, kp, vp, nullptr, nullptr);
  transpose_v<<<dim3(LSEQ/64, BATCH*HEADS), 256, 0, stream>>>(vp, vt);
  attn<<<dim3((LSEQ/64)*HEADS*BATCH), 256, 0, stream>>>(qp, kp, vt, pbb, ao);
  gemm128<1><<<dim3(D_MODEL/128, MTOT/128, 1), 256, 0, stream>>>(
      ao, nullptr, nullptr, wot, nullptr, nullptr, nullptr, nullptr, nullptr, bo, out);
}

// Round 3
// 563.668 us; speedup vs baseline: 1.4381x; 1.2433x over previous
//
#include <hip/hip_runtime.h>
#include <hip/hip_bf16.h>

#define D_MODEL 768
#define HEADS 12
#define DK 64
#define LSEQ 2048
#define BATCH 4
#define MTOT (BATCH*LSEQ)                  // 8192 rows
#define SCALING 0.35355339059327373f       // 64^-0.25
#define LOG2E 1.4426950408889634f
#define NT (LSEQ/64)

typedef unsigned short ushort_t;
typedef __attribute__((ext_vector_type(8))) short bf16x8;
typedef __attribute__((ext_vector_type(4))) float f32x4;
typedef __attribute__((ext_vector_type(8))) unsigned short ushort8;
typedef __attribute__((ext_vector_type(4))) unsigned short ushort4v;

__device__ __forceinline__ unsigned short f2bf(float f){
  union { float f; unsigned int u; } v; v.f = f;
  unsigned int r = v.u + 0x7fffu + ((v.u >> 16) & 1u);
  return (unsigned short)(r >> 16);
}

__device__ __forceinline__ float bf2f(unsigned short u){
  union { unsigned int u; float f; } v; v.u = ((unsigned int)u) << 16; return v.f;
}

__device__ __forceinline__ float exp2_fast(float x){
#if __has_builtin(__builtin_amdgcn_exp2f)
  return __builtin_amdgcn_exp2f(x);
#else
  return __expf(x * 0.69314718055994531f);
#endif
}

__device__ __forceinline__ void g2l16(const void* g, void* l){
  __builtin_amdgcn_global_load_lds((const __attribute__((address_space(1))) void*)g,
                                   (__attribute__((address_space(3))) void*)l, 16, 0, 0);
}

// swizzled LDS read: logical (row, 16B-chunk c16) -> physical chunk c16 ^ (row&7)
__device__ __forceinline__ bf16x8 ldswz(const ushort_t* base, int row, int c16){
  return *(const bf16x8*)((const char*)base + row*128 + (((c16) ^ (row & 7)) << 4));
}

// ---------------- pass A1: fp32 -> bf16 input conversion ----------------
__global__ __launch_bounds__(256) void convert_inputs(
    const float* __restrict__ q, const float* __restrict__ k, const float* __restrict__ v,
    ushort_t* __restrict__ oq, ushort_t* __restrict__ ok, ushort_t* __restrict__ ov){
  const float* s = blockIdx.z==0 ? q : (blockIdx.z==1 ? k : v);
  ushort_t* d    = blockIdx.z==0 ? oq : (blockIdx.z==1 ? ok : ov);
  size_t i = ((size_t)blockIdx.x*256 + threadIdx.x)*4;
  float4 f = *(const float4*)(s + i);
  ushort4v o; o.x=f2bf(f.x); o.y=f2bf(f.y); o.z=f2bf(f.z); o.w=f2bf(f.w);
  *(ushort4v*)(d + i) = o;
}

// ---------------- pass A1b: posbias fp32 -> bf16, x log2e, PRE-TILED ----------------
// layout: [h][qt][t][w][g][li] -> 16 contiguous bf16 = [r*4+nt]
__global__ __launch_bounds__(256) void convert_bias(
    const float* __restrict__ pb, ushort_t* __restrict__ o){
  int t = blockIdx.x, qt = blockIdx.y, h = blockIdx.z;
  int tid = threadIdx.x, w = tid>>6, lane = tid&63, g = lane>>4, li = lane&15;
  const float* src = pb + ((size_t)h*LSEQ + qt*64 + w*16 + g*4)*LSEQ + t*64 + li;
  ushort_t* dst = o + ((((size_t)h*32 + qt)*32 + t)<<12) + w*1024 + g*256 + li*16;
  ushort8 v0, v1;
  #pragma unroll
  for (int r=0;r<4;r++){
    #pragma unroll
    for (int nt=0;nt<4;nt++){
      float f = src[(size_t)r*LSEQ + nt*16] * LOG2E;
      int idx = r*4+nt;
      if (idx < 8) v0[idx] = f2bf(f); else v1[idx-8] = f2bf(f);
    }
  }
  *(ushort8*)(dst)   = v0;
  *(ushort8*)(dst+8) = v1;
}

// ---------------- pass A2: weight transpose fp32[k][n] -> bf16[n][k] ----------------
__global__ __launch_bounds__(256) void transpose_w(
    const float* __restrict__ w0, const float* __restrict__ w1,
    const float* __restrict__ w2, const float* __restrict__ w3,
    ushort_t* __restrict__ o0, ushort_t* __restrict__ o1,
    ushort_t* __restrict__ o2, ushort_t* __restrict__ o3){
  const float* s; ushort_t* d;
  switch (blockIdx.z){
    case 0: s=w0; d=o0; break; case 1: s=w1; d=o1; break;
    case 2: s=w2; d=o2; break; default: s=w3; d=o3; break;
  }
  __shared__ float t[32][33];
  int tx = threadIdx.x, ty = threadIdx.y;
  int c0 = blockIdx.x*32, r0 = blockIdx.y*32;
  #pragma unroll
  for (int i=0;i<4;i++) t[ty*4+i][tx] = s[(size_t)(r0+ty*4+i)*D_MODEL + c0+tx];
  __syncthreads();
  #pragma unroll
  for (int i=0;i<4;i++) d[(size_t)(c0+ty*4+i)*D_MODEL + r0+tx] = f2bf(t[tx][ty*4+i]);
}

// ---------------- GEMM: C[M][N] = A[M][K] * Bt[N][K]^T ----------------
template<int MODE>
__global__ __launch_bounds__(256) void gemm128(
    const ushort_t* __restrict__ A0, const ushort_t* __restrict__ A1, const ushort_t* __restrict__ A2,
    const ushort_t* __restrict__ B0, const ushort_t* __restrict__ B1, const ushort_t* __restrict__ B2,
    ushort_t* __restrict__ o0, ushort_t* __restrict__ o1, ushort_t* __restrict__ o2,
    const float* __restrict__ bias, float* __restrict__ outf)
{
  const ushort_t* A; const ushort_t* Bt; ushort_t* outb = nullptr; float scale = 1.f;
  if (MODE == 0){
    int z = blockIdx.z;
    A  = z==0 ? A0 : (z==1 ? A1 : A2);
    Bt = z==0 ? B0 : (z==1 ? B1 : B2);
    outb = z==0 ? o0 : (z==1 ? o1 : o2);
    scale = (z==0) ? SCALING*LOG2E : (z==1 ? SCALING : 1.f);   // fold log2e into Q
  } else { A = A0; Bt = B0; }

  __shared__ ushort_t As[128*64];
  __shared__ ushort_t Bs[128*64];
  int tid = threadIdx.x;
  int w = tid >> 6, lane = tid & 63;
  int wm = w >> 1, wn = w & 1;
  int g = lane >> 4, li = lane & 15;
  size_t m0 = (size_t)blockIdx.y * 128;
  size_t n0 = (size_t)blockIdx.x * 128;

  f32x4 acc[4][4] = {};

  for (int kt = 0; kt < D_MODEL/64; ++kt){
    __syncthreads();
    int k0 = kt*64;
    #pragma unroll
    for (int i=0;i<4;i++){
      int row = i*32 + w*8 + (lane>>3);
      int c = (lane & 7) ^ (row & 7);
      g2l16(A  + (m0 + row)*D_MODEL + k0 + c*8, As + (i*32 + w*8)*64);
      g2l16(Bt + (n0 + row)*D_MODEL + k0 + c*8, Bs + (i*32 + w*8)*64);
    }
    __syncthreads();
    #pragma unroll
    for (int kc=0;kc<2;kc++){
      bf16x8 a[4], b[4];
      #pragma unroll
      for (int mt=0;mt<4;mt++) a[mt] = ldswz(As, wm*64 + mt*16 + li, kc*4 + g);
      #pragma unroll
      for (int nt=0;nt<4;nt++) b[nt] = ldswz(Bs, wn*64 + nt*16 + li, kc*4 + g);
      #pragma unroll
      for (int mt=0;mt<4;mt++)
        #pragma unroll
        for (int nt=0;nt<4;nt++)
          acc[mt][nt] = __builtin_amdgcn_mfma_f32_16x16x32_bf16(a[mt], b[nt], acc[mt][nt], 0,0,0);
    }
  }

  #pragma unroll
  for (int mt=0;mt<4;mt++){
    #pragma unroll
    for (int nt=0;nt<4;nt++){
      #pragma unroll
      for (int r=0;r<4;r++){
        int m = (int)m0 + wm*64 + mt*16 + g*4 + r;
        int n = (int)n0 + wn*64 + nt*16 + li;
        float v = acc[mt][nt][r];
        if (MODE == 0){
          v *= scale;
          int bb = m >> 11, l = m & (LSEQ-1), hh = n >> 6, dd = n & 63;
          outb[((((size_t)bb*HEADS + hh)*LSEQ + l) << 6) + dd] = f2bf(v);
        } else {
          outf[(size_t)m*D_MODEL + n] = v + bias[n];
        }
      }
    }
  }
}

// ---------------- pass B2: V [b][h][l][d] -> Vt [b][h][d][l] ----------------
__global__ __launch_bounds__(256) void transpose_v(
    const ushort_t* __restrict__ vp, ushort_t* __restrict__ vt){
  __shared__ ushort_t tile[64][65];
  int tid = threadIdx.x;
  int lt = blockIdx.x;
  size_t bh = blockIdx.y;
  const ushort_t* src = vp + (bh*LSEQ + (size_t)lt*64)*64;
  #pragma unroll
  for (int i=0;i<2;i++){
    int row = i*32 + (tid>>3);
    int c = tid & 7;
    ushort8 vv = *(const ushort8*)(src + row*64 + c*8);
    #pragma unroll
    for (int j=0;j<8;j++) tile[row][c*8+j] = vv[j];
  }
  __syncthreads();
  ushort_t* dst = vt + bh*64*LSEQ + (size_t)lt*64;
  #pragma unroll
  for (int i=0;i<2;i++){
    int d = i*32 + (tid>>3);
    int c = tid & 7;
    ushort8 vv;
    #pragma unroll
    for (int j=0;j<8;j++) vv[j] = tile[c*8+j][d];
    *(ushort8*)(dst + (size_t)d*LSEQ + c*8) = vv;
  }
}

// ---------------- pass C: flash attention (no-max softmax, exp2 domain) ----------------
// block = 1 (b,h,qtile of 64 rows), 4 waves x 16 q-rows. KV tiles of 64.
__global__ __launch_bounds__(256, 4) void attn(
    const ushort_t* __restrict__ Q, const ushort_t* __restrict__ Kp,
    const ushort_t* __restrict__ Vt, const ushort_t* __restrict__ PBT,
    ushort_t* __restrict__ AO)
{
  __shared__ ushort_t ks[2][64*64];
  __shared__ ushort_t vs[2][64*64];
  __shared__ ushort_t ps[4][16*64];
  int tid = threadIdx.x, w = tid >> 6, lane = tid & 63;
  int g = lane >> 4, li = lane & 15;
  int bidx = blockIdx.x;
  int b = bidx & 3;                // batch fastest -> 4 batches stream same posbias -> L3 reuse
  int h = (bidx >> 2) % HEADS;
  int qt = bidx / (4*HEADS);
  size_t bh = (size_t)b*HEADS + h;
  const ushort_t* qb = Q  + bh*(LSEQ*64);
  const ushort_t* kb = Kp + bh*(LSEQ*64);
  const ushort_t* vb = Vt + bh*(64*LSEQ);
  const ushort_t* pbt = PBT + ((((size_t)h*32 + qt)*32)<<12) + w*1024 + g*256 + li*16;

  int q0 = qt*64 + w*16;
  bf16x8 qf[2];
  #pragma unroll
  for (int kc=0;kc<2;kc++)
    qf[kc] = *(const bf16x8*)(qb + (size_t)(q0 + li)*64 + kc*32 + g*8);

  f32x4 oa[4] = {};
  float lsum[4] = {0.f, 0.f, 0.f, 0.f};

  auto stage = [&](int t, int buf){
    #pragma unroll
    for (int i=0;i<2;i++){
      int row = i*32 + w*8 + (lane>>3);
      int c = (lane & 7) ^ (row & 7);
      g2l16(kb + ((size_t)t*64 + row)*64 + c*8, &ks[buf][(i*32 + w*8)*64]);
      g2l16(vb + (size_t)row*LSEQ + t*64 + c*8, &vs[buf][(i*32 + w*8)*64]);
    }
  };

  stage(0, 0);
  ushort8 bc0 = *(const ushort8*)(pbt);
  ushort8 bc1 = *(const ushort8*)(pbt + 8);
  ushort8 bn0, bn1;
  __syncthreads();

  for (int t=0; t<NT; ++t){
    int buf = t & 1;
    if (t+1 < NT){
      stage(t+1, buf^1);
      bn0 = *(const ushort8*)(pbt + ((size_t)(t+1)<<12));
      bn1 = *(const ushort8*)(pbt + ((size_t)(t+1)<<12) + 8);
    }

    // S = Q K^T (SCALING and log2e pre-baked into Q,K)
    f32x4 s[4] = {};
    __builtin_amdgcn_s_setprio(1);
    #pragma unroll
    for (int kc=0;kc<2;kc++){
      #pragma unroll
      for (int nt=0;nt<4;nt++){
        bf16x8 kf = ldswz(ks[buf], nt*16 + li, kc*4 + g);
        s[nt] = __builtin_amdgcn_mfma_f32_16x16x32_bf16(qf[kc], kf, s[nt], 0,0,0);
      }
    }
    __builtin_amdgcn_s_setprio(0);

    // p = 2^(S + bias); accumulate per-lane row partial sums; P -> per-wave LDS
    #pragma unroll
    for (int r=0;r<4;r++){
      int row = g*4 + r;
      #pragma unroll
      for (int nt=0;nt<4;nt++){
        int idx = r*4 + nt;
        float bias = bf2f(idx < 8 ? bc0[idx] : bc1[idx-8]);
        float p = exp2_fast(s[nt][r] + bias);
        lsum[r] += p;
        int colb = (nt*16 + li)*2;
        *(ushort_t*)((char*)ps[w] + row*128 + (colb ^ ((row&7)<<4))) = f2bf(p);
      }
    }

    // O += P V   (same-wave DS ops are in-order, no barrier needed)
    bf16x8 pa[2];
    #pragma unroll
    for (int kc=0;kc<2;kc++) pa[kc] = ldswz(ps[w], li, kc*4 + g);
    __builtin_amdgcn_s_setprio(1);
    #pragma unroll
    for (int kc=0;kc<2;kc++){
      #pragma unroll
      for (int nt=0;nt<4;nt++){
        bf16x8 vf = ldswz(vs[buf], nt*16 + li, kc*4 + g);
        oa[nt] = __builtin_amdgcn_mfma_f32_16x16x32_bf16(pa[kc], vf, oa[nt], 0,0,0);
      }
    }
    __builtin_amdgcn_s_setprio(0);
    __syncthreads();
    bc0 = bn0; bc1 = bn1;
  }

  #pragma unroll
  for (int r=0;r<4;r++){
    float rs = lsum[r];
    #pragma unroll
    for (int d=1; d<16; d<<=1) rs += __shfl_xor(rs, d);
    float inv = 1.f / rs;
    size_t orow = ((size_t)b*LSEQ + q0 + g*4 + r)*D_MODEL + h*64;
    #pragma unroll
    for (int nt=0;nt<4;nt++)
      AO[orow + nt*16 + li] = f2bf(oa[nt][r] * inv);
  }
}

// ---------------- launcher ----------------
extern "C" void kernel_launch(void* const* d_in, const int* in_sizes, int n_in,
                              void* d_out, int out_size, void* d_ws, size_t ws_size,
                              hipStream_t stream){
  const float* q  = (const float*)d_in[0];
  const float* k  = (const float*)d_in[1];
  const float* v  = (const float*)d_in[2];
  const float* pb = (const float*)d_in[3];
  const float* Wq = (const float*)d_in[4];
  const float* Wk = (const float*)d_in[5];
  const float* Wv = (const float*)d_in[6];
  const float* Wo = (const float*)d_in[7];
  const float* bo = (const float*)d_in[8];
  float* out = (float*)d_out;

  char* ws = (char*)d_ws;
  size_t off = 0;
  const size_t XSZ = (size_t)MTOT*D_MODEL*2;   // 12.58 MB
  const size_t WSZ = (size_t)D_MODEL*D_MODEL*2;
  const size_t PBSZ = (size_t)HEADS*LSEQ*LSEQ*2; // 100.66 MB
  ushort_t* xq  = (ushort_t*)(ws + off); off += XSZ;
  ushort_t* xk  = (ushort_t*)(ws + off); off += XSZ;
  ushort_t* xv  = (ushort_t*)(ws + off); off += XSZ;
  ushort_t* wqt = (ushort_t*)(ws + off); off += WSZ;
  ushort_t* wkt = (ushort_t*)(ws + off); off += WSZ;
  ushort_t* wvt = (ushort_t*)(ws + off); off += WSZ;
  ushort_t* wot = (ushort_t*)(ws + off); off += WSZ;
  ushort_t* qp  = (ushort_t*)(ws + off); off += XSZ;
  ushort_t* kp  = (ushort_t*)(ws + off); off += XSZ;
  ushort_t* vp  = (ushort_t*)(ws + off); off += XSZ;
  ushort_t* vt  = (ushort_t*)(ws + off); off += XSZ;
  ushort_t* ao  = (ushort_t*)(ws + off); off += XSZ;
  ushort_t* pbt = (ushort_t*)(ws + off); off += PBSZ;

  convert_inputs<<<dim3(MTOT*D_MODEL/1024, 1, 3), 256, 0, stream>>>(q, k, v, xq, xk, xv);
  convert_bias<<<dim3(32, 32, HEADS), 256, 0, stream>>>(pb, pbt);
  transpose_w<<<dim3(24, 24, 4), dim3(32, 8), 0, stream>>>(Wq, Wk, Wv, Wo, wqt, wkt, wvt, wot);
  gemm128<0><<<dim3(D_MODEL/128, MTOT/128, 3), 256, 0, stream>>>(
      xq, xk, xv, wqt, wkt, wvt, qp, kp, vp, nullptr, nullptr);
  transpose_v<<<dim3(LSEQ/64, BATCH*HEADS), 256, 0, stream>>>(vp, vt);
  attn<<<dim3((LSEQ/64)*HEADS*BATCH), 256, 0, stream>>>(qp, kp, vt, pbt, ao);
  gemm128<1><<<dim3(D_MODEL/128, MTOT/128, 1), 256, 0, stream>>>(
      ao, nullptr, nullptr, wot, nullptr, nullptr, nullptr, nullptr, nullptr, bo, out);
}

// Round 4
// 561.234 us; speedup vs baseline: 1.4444x; 1.0043x over previous
//
#include <hip/hip_runtime.h>
#include <hip/hip_bf16.h>

#define D_MODEL 768
#define HEADS 12
#define DK 64
#define LSEQ 2048
#define BATCH 4
#define MTOT (BATCH*LSEQ)                  // 8192 rows
#define SCALING 0.35355339059327373f       // 64^-0.25
#define LOG2E 1.4426950408889634f
#define NT (LSEQ/64)

typedef unsigned short ushort_t;
typedef __attribute__((ext_vector_type(8))) short bf16x8;
typedef __attribute__((ext_vector_type(4))) float f32x4;
typedef __attribute__((ext_vector_type(8))) unsigned short ushort8;
typedef __attribute__((ext_vector_type(4))) unsigned short ushort4v;

// RNE fp32->bf16 via hip intrinsic (ROCm7: round-nearest-even, compiler packs pairs)
__device__ __forceinline__ ushort_t f2bf(float f){
  __hip_bfloat16 h = __float2bfloat16(f);
  return __builtin_bit_cast(ushort_t, h);
}

__device__ __forceinline__ float bf2f(unsigned short u){
  union { unsigned int u; float f; } v; v.u = ((unsigned int)u) << 16; return v.f;
}

__device__ __forceinline__ float exp2_fast(float x){
#if __has_builtin(__builtin_amdgcn_exp2f)
  return __builtin_amdgcn_exp2f(x);
#else
  return __expf(x * 0.69314718055994531f);
#endif
}

__device__ __forceinline__ void g2l16(const void* g, void* l){
  __builtin_amdgcn_global_load_lds((const __attribute__((address_space(1))) void*)g,
                                   (__attribute__((address_space(3))) void*)l, 16, 0, 0);
}

// swizzled LDS read: logical (row, 16B-chunk c16) -> physical chunk c16 ^ (row&7)
__device__ __forceinline__ bf16x8 ldswz(const ushort_t* base, int row, int c16){
  return *(const bf16x8*)((const char*)base + row*128 + (((c16) ^ (row & 7)) << 4));
}

// ---------------- pass A1: fp32 -> bf16 input conversion ----------------
__global__ __launch_bounds__(256) void convert_inputs(
    const float* __restrict__ q, const float* __restrict__ k, const float* __restrict__ v,
    ushort_t* __restrict__ oq, ushort_t* __restrict__ ok, ushort_t* __restrict__ ov){
  const float* s = blockIdx.z==0 ? q : (blockIdx.z==1 ? k : v);
  ushort_t* d    = blockIdx.z==0 ? oq : (blockIdx.z==1 ? ok : ov);
  size_t i = ((size_t)blockIdx.x*256 + threadIdx.x)*4;
  float4 f = *(const float4*)(s + i);
  ushort4v o; o.x=f2bf(f.x); o.y=f2bf(f.y); o.z=f2bf(f.z); o.w=f2bf(f.w);
  *(ushort4v*)(d + i) = o;
}

// ---------------- pass A1b: posbias fp32 -> bf16, x log2e, PRE-TILED ----------------
// block = one (h,qt,t) 64x64 tile; coalesced float4 reads via padded-LDS transpose,
// coalesced 32B/lane writes. layout: [h][qt][t][w][g][li] -> 16 bf16 = [r*4+nt]
__global__ __launch_bounds__(256) void convert_bias(
    const float* __restrict__ pb, ushort_t* __restrict__ o){
  int t = blockIdx.x, qt = blockIdx.y, h = blockIdx.z;
  __shared__ float ld[64][65];
  int tid = threadIdx.x;
  const float* src = pb + ((size_t)h*LSEQ + qt*64)*LSEQ + (size_t)t*64;
  #pragma unroll
  for (int j=0;j<4;j++){
    int idx = j*256 + tid;
    int row = idx >> 4, c4 = idx & 15;
    float4 f = *(const float4*)(src + (size_t)row*LSEQ + c4*4);
    ld[row][c4*4+0]=f.x; ld[row][c4*4+1]=f.y; ld[row][c4*4+2]=f.z; ld[row][c4*4+3]=f.w;
  }
  __syncthreads();
  int w = tid>>6, lane = tid&63, g = lane>>4, li = lane&15;
  ushort_t* dst = o + ((((size_t)h*32 + qt)*32 + t)<<12) + w*1024 + g*256 + li*16;
  ushort8 v0, v1;
  #pragma unroll
  for (int r=0;r<4;r++){
    #pragma unroll
    for (int nt=0;nt<4;nt++){
      float f = ld[w*16 + g*4 + r][nt*16 + li] * LOG2E;
      int idx = r*4+nt;
      if (idx < 8) v0[idx] = f2bf(f); else v1[idx-8] = f2bf(f);
    }
  }
  *(ushort8*)(dst)   = v0;
  *(ushort8*)(dst+8) = v1;
}

// ---------------- pass A2: weight transpose fp32[k][n] -> bf16[n][k] ----------------
__global__ __launch_bounds__(256) void transpose_w(
    const float* __restrict__ w0, const float* __restrict__ w1,
    const float* __restrict__ w2, const float* __restrict__ w3,
    ushort_t* __restrict__ o0, ushort_t* __restrict__ o1,
    ushort_t* __restrict__ o2, ushort_t* __restrict__ o3){
  const float* s; ushort_t* d;
  switch (blockIdx.z){
    case 0: s=w0; d=o0; break; case 1: s=w1; d=o1; break;
    case 2: s=w2; d=o2; break; default: s=w3; d=o3; break;
  }
  __shared__ float t[32][33];
  int tx = threadIdx.x, ty = threadIdx.y;
  int c0 = blockIdx.x*32, r0 = blockIdx.y*32;
  #pragma unroll
  for (int i=0;i<4;i++) t[ty*4+i][tx] = s[(size_t)(r0+ty*4+i)*D_MODEL + c0+tx];
  __syncthreads();
  #pragma unroll
  for (int i=0;i<4;i++) d[(size_t)(c0+ty*4+i)*D_MODEL + r0+tx] = f2bf(t[tx][ty*4+i]);
}

// ---------------- GEMM: C[M][N] = A[M][K] * Bt[N][K]^T ----------------
template<int MODE>
__global__ __launch_bounds__(256) void gemm128(
    const ushort_t* __restrict__ A0, const ushort_t* __restrict__ A1, const ushort_t* __restrict__ A2,
    const ushort_t* __restrict__ B0, const ushort_t* __restrict__ B1, const ushort_t* __restrict__ B2,
    ushort_t* __restrict__ o0, ushort_t* __restrict__ o1, ushort_t* __restrict__ o2,
    const float* __restrict__ bias, float* __restrict__ outf)
{
  const ushort_t* A; const ushort_t* Bt; ushort_t* outb = nullptr; float scale = 1.f;
  if (MODE == 0){
    int z = blockIdx.z;
    A  = z==0 ? A0 : (z==1 ? A1 : A2);
    Bt = z==0 ? B0 : (z==1 ? B1 : B2);
    outb = z==0 ? o0 : (z==1 ? o1 : o2);
    scale = (z==0) ? SCALING*LOG2E : (z==1 ? SCALING : 1.f);   // fold log2e into Q
  } else { A = A0; Bt = B0; }

  __shared__ ushort_t As[128*64];
  __shared__ ushort_t Bs[128*64];
  int tid = threadIdx.x;
  int w = tid >> 6, lane = tid & 63;
  int wm = w >> 1, wn = w & 1;
  int g = lane >> 4, li = lane & 15;
  size_t m0 = (size_t)blockIdx.y * 128;
  size_t n0 = (size_t)blockIdx.x * 128;

  f32x4 acc[4][4] = {};

  for (int kt = 0; kt < D_MODEL/64; ++kt){
    __syncthreads();
    int k0 = kt*64;
    #pragma unroll
    for (int i=0;i<4;i++){
      int row = i*32 + w*8 + (lane>>3);
      int c = (lane & 7) ^ (row & 7);
      g2l16(A  + (m0 + row)*D_MODEL + k0 + c*8, As + (i*32 + w*8)*64);
      g2l16(Bt + (n0 + row)*D_MODEL + k0 + c*8, Bs + (i*32 + w*8)*64);
    }
    __syncthreads();
    #pragma unroll
    for (int kc=0;kc<2;kc++){
      bf16x8 a[4], b[4];
      #pragma unroll
      for (int mt=0;mt<4;mt++) a[mt] = ldswz(As, wm*64 + mt*16 + li, kc*4 + g);
      #pragma unroll
      for (int nt=0;nt<4;nt++) b[nt] = ldswz(Bs, wn*64 + nt*16 + li, kc*4 + g);
      #pragma unroll
      for (int mt=0;mt<4;mt++)
        #pragma unroll
        for (int nt=0;nt<4;nt++)
          acc[mt][nt] = __builtin_amdgcn_mfma_f32_16x16x32_bf16(a[mt], b[nt], acc[mt][nt], 0,0,0);
    }
  }

  #pragma unroll
  for (int mt=0;mt<4;mt++){
    #pragma unroll
    for (int nt=0;nt<4;nt++){
      #pragma unroll
      for (int r=0;r<4;r++){
        int m = (int)m0 + wm*64 + mt*16 + g*4 + r;
        int n = (int)n0 + wn*64 + nt*16 + li;
        float v = acc[mt][nt][r];
        if (MODE == 0){
          v *= scale;
          int bb = m >> 11, l = m & (LSEQ-1), hh = n >> 6, dd = n & 63;
          outb[((((size_t)bb*HEADS + hh)*LSEQ + l) << 6) + dd] = f2bf(v);
        } else {
          outf[(size_t)m*D_MODEL + n] = v + bias[n];
        }
      }
    }
  }
}

// ---------------- pass B2: V [b][h][l][d] -> Vt [b][h][d][l] ----------------
__global__ __launch_bounds__(256) void transpose_v(
    const ushort_t* __restrict__ vp, ushort_t* __restrict__ vt){
  __shared__ ushort_t tile[64][65];
  int tid = threadIdx.x;
  int lt = blockIdx.x;
  size_t bh = blockIdx.y;
  const ushort_t* src = vp + (bh*LSEQ + (size_t)lt*64)*64;
  #pragma unroll
  for (int i=0;i<2;i++){
    int row = i*32 + (tid>>3);
    int c = tid & 7;
    ushort8 vv = *(const ushort8*)(src + row*64 + c*8);
    #pragma unroll
    for (int j=0;j<8;j++) tile[row][c*8+j] = vv[j];
  }
  __syncthreads();
  ushort_t* dst = vt + bh*64*LSEQ + (size_t)lt*64;
  #pragma unroll
  for (int i=0;i<2;i++){
    int d = i*32 + (tid>>3);
    int c = tid & 7;
    ushort8 vv;
    #pragma unroll
    for (int j=0;j<8;j++) vv[j] = tile[c*8+j][d];
    *(ushort8*)(dst + (size_t)d*LSEQ + c*8) = vv;
  }
}

// ---------------- pass C: flash attention (no-max softmax, exp2 domain) ----------------
// block = 1 (b,h,qtile of 64 rows), 4 waves x 16 q-rows. KV tiles of 64.
// bias rides a register prefetch pipeline; MFMA C-init absorbs the bias add.
__global__ __launch_bounds__(256, 4) void attn(
    const ushort_t* __restrict__ Q, const ushort_t* __restrict__ Kp,
    const ushort_t* __restrict__ Vt, const ushort_t* __restrict__ PBT,
    ushort_t* __restrict__ AO)
{
  __shared__ ushort_t ks[2][64*64];
  __shared__ ushort_t vs[2][64*64];
  __shared__ ushort_t ps[4][16*64];
  int tid = threadIdx.x, w = tid >> 6, lane = tid & 63;
  int g = lane >> 4, li = lane & 15;
  int bidx = blockIdx.x;
  int b = bidx & 3;                // batch fastest -> 4 batches stream same posbias -> L3 reuse
  int h = (bidx >> 2) % HEADS;
  int qt = bidx / (4*HEADS);
  size_t bh = (size_t)b*HEADS + h;
  const ushort_t* qb = Q  + bh*(LSEQ*64);
  const ushort_t* kb = Kp + bh*(LSEQ*64);
  const ushort_t* vb = Vt + bh*(64*LSEQ);
  const ushort_t* pbt = PBT + ((((size_t)h*32 + qt)*32)<<12) + w*1024 + g*256 + li*16;

  int q0 = qt*64 + w*16;
  bf16x8 qf[2];
  #pragma unroll
  for (int kc=0;kc<2;kc++)
    qf[kc] = *(const bf16x8*)(qb + (size_t)(q0 + li)*64 + kc*32 + g*8);

  f32x4 oa[4] = {};
  float lsum[4] = {0.f, 0.f, 0.f, 0.f};

  auto stage = [&](int t, int buf){
    #pragma unroll
    for (int i=0;i<2;i++){
      int row = i*32 + w*8 + (lane>>3);
      int c = (lane & 7) ^ (row & 7);
      g2l16(kb + ((size_t)t*64 + row)*64 + c*8, &ks[buf][(i*32 + w*8)*64]);
      g2l16(vb + (size_t)row*LSEQ + t*64 + c*8, &vs[buf][(i*32 + w*8)*64]);
    }
  };

  stage(0, 0);
  ushort8 bc0 = *(const ushort8*)(pbt);
  ushort8 bc1 = *(const ushort8*)(pbt + 8);
  ushort8 bn0, bn1;
  __syncthreads();

  for (int t=0; t<NT; ++t){
    int buf = t & 1;
    if (t+1 < NT){
      stage(t+1, buf^1);
      bn0 = *(const ushort8*)(pbt + ((size_t)(t+1)<<12));
      bn1 = *(const ushort8*)(pbt + ((size_t)(t+1)<<12) + 8);
    }

    // S starts at the posbias tile (MFMA C-in is free), then += Q K^T
    f32x4 s[4];
    #pragma unroll
    for (int nt=0;nt<4;nt++)
      #pragma unroll
      for (int r=0;r<4;r++){
        int idx = r*4 + nt;
        s[nt][r] = bf2f(idx < 8 ? bc0[idx] : bc1[idx-8]);
      }
    __builtin_amdgcn_s_setprio(1);
    #pragma unroll
    for (int kc=0;kc<2;kc++){
      #pragma unroll
      for (int nt=0;nt<4;nt++){
        bf16x8 kf = ldswz(ks[buf], nt*16 + li, kc*4 + g);
        s[nt] = __builtin_amdgcn_mfma_f32_16x16x32_bf16(qf[kc], kf, s[nt], 0,0,0);
      }
    }
    __builtin_amdgcn_s_setprio(0);

    // p = 2^s; accumulate per-lane row partial sums; P -> per-wave LDS
    #pragma unroll
    for (int r=0;r<4;r++){
      int row = g*4 + r;
      #pragma unroll
      for (int nt=0;nt<4;nt++){
        float p = exp2_fast(s[nt][r]);
        lsum[r] += p;
        int colb = (nt*16 + li)*2;
        *(ushort_t*)((char*)ps[w] + row*128 + (colb ^ ((row&7)<<4))) = f2bf(p);
      }
    }

    // O += P V   (same-wave DS ops are in-order, no barrier needed)
    bf16x8 pa[2];
    #pragma unroll
    for (int kc=0;kc<2;kc++) pa[kc] = ldswz(ps[w], li, kc*4 + g);
    __builtin_amdgcn_s_setprio(1);
    #pragma unroll
    for (int kc=0;kc<2;kc++){
      #pragma unroll
      for (int nt=0;nt<4;nt++){
        bf16x8 vf = ldswz(vs[buf], nt*16 + li, kc*4 + g);
        oa[nt] = __builtin_amdgcn_mfma_f32_16x16x32_bf16(pa[kc], vf, oa[nt], 0,0,0);
      }
    }
    __builtin_amdgcn_s_setprio(0);
    __syncthreads();
    bc0 = bn0; bc1 = bn1;
  }

  #pragma unroll
  for (int r=0;r<4;r++){
    float rs = lsum[r];
    #pragma unroll
    for (int d=1; d<16; d<<=1) rs += __shfl_xor(rs, d);
    float inv = 1.f / rs;
    size_t orow = ((size_t)b*LSEQ + q0 + g*4 + r)*D_MODEL + h*64;
    #pragma unroll
    for (int nt=0;nt<4;nt++)
      AO[orow + nt*16 + li] = f2bf(oa[nt][r] * inv);
  }
}

// ---------------- launcher ----------------
extern "C" void kernel_launch(void* const* d_in, const int* in_sizes, int n_in,
                              void* d_out, int out_size, void* d_ws, size_t ws_size,
                              hipStream_t stream){
  const float* q  = (const float*)d_in[0];
  const float* k  = (const float*)d_in[1];
  const float* v  = (const float*)d_in[2];
  const float* pb = (const float*)d_in[3];
  const float* Wq = (const float*)d_in[4];
  const float* Wk = (const float*)d_in[5];
  const float* Wv = (const float*)d_in[6];
  const float* Wo = (const float*)d_in[7];
  const float* bo = (const float*)d_in[8];
  float* out = (float*)d_out;

  char* ws = (char*)d_ws;
  size_t off = 0;
  const size_t XSZ = (size_t)MTOT*D_MODEL*2;   // 12.58 MB
  const size_t WSZ = (size_t)D_MODEL*D_MODEL*2;
  const size_t PBSZ = (size_t)HEADS*LSEQ*LSEQ*2; // 100.66 MB
  ushort_t* xq  = (ushort_t*)(ws + off); off += XSZ;
  ushort_t* xk  = (ushort_t*)(ws + off); off += XSZ;
  ushort_t* xv  = (ushort_t*)(ws + off); off += XSZ;
  ushort_t* wqt = (ushort_t*)(ws + off); off += WSZ;
  ushort_t* wkt = (ushort_t*)(ws + off); off += WSZ;
  ushort_t* wvt = (ushort_t*)(ws + off); off += WSZ;
  ushort_t* wot = (ushort_t*)(ws + off); off += WSZ;
  ushort_t* qp  = (ushort_t*)(ws + off); off += XSZ;
  ushort_t* kp  = (ushort_t*)(ws + off); off += XSZ;
  ushort_t* vp  = (ushort_t*)(ws + off); off += XSZ;
  ushort_t* vt  = (ushort_t*)(ws + off); off += XSZ;
  ushort_t* ao  = (ushort_t*)(ws + off); off += XSZ;
  ushort_t* pbt = (ushort_t*)(ws + off); off += PBSZ;

  convert_inputs<<<dim3(MTOT*D_MODEL/1024, 1, 3), 256, 0, stream>>>(q, k, v, xq, xk, xv);
  convert_bias<<<dim3(32, 32, HEADS), 256, 0, stream>>>(pb, pbt);
  transpose_w<<<dim3(24, 24, 4), dim3(32, 8), 0, stream>>>(Wq, Wk, Wv, Wo, wqt, wkt, wvt, wot);
  gemm128<0><<<dim3(D_MODEL/128, MTOT/128, 3), 256, 0, stream>>>(
      xq, xk, xv, wqt, wkt, wvt, qp, kp, vp, nullptr, nullptr);
  transpose_v<<<dim3(LSEQ/64, BATCH*HEADS), 256, 0, stream>>>(vp, vt);
  attn<<<dim3((LSEQ/64)*HEADS*BATCH), 256, 0, stream>>>(qp, kp, vt, pbt, ao);
  gemm128<1><<<dim3(D_MODEL/128, MTOT/128, 1), 256, 0, stream>>>(
      ao, nullptr, nullptr, wot, nullptr, nullptr, nullptr, nullptr, nullptr, bo, out);
}